// Round 1
// 1509.098 us; speedup vs baseline: 2.1725x; 2.1725x over previous
//
#include <hip/hip_runtime.h>
#include <cstdint>
#include <cstddef>

#define NN 10000
#define NE 320000
#define LN_EPS 1e-5f

typedef short bf16x8 __attribute__((ext_vector_type(8)));
typedef float f32x4 __attribute__((ext_vector_type(4)));

#define A0_STRIDE 40
#define A_STRIDE 264

// wB ushort offsets
#define OFF_CONV0 0
#define OFF_CONV13 2048
#define OFF_IE1 51200   // 4 layers x (6ks x 4nt x 512) = 4 x 12288
#define OFF_IE2 100352  // 4 layers x (2ks x 4nt x 512) = 4 x 4096
#define OFF_EM1 116736  // 5ks x 8nt x 512 = 20480
#define OFF_EM2 137216  // 4ks x 4nt x 512 = 8192
#define WB_TOTAL 145408

// ---------------- helpers ----------------

__device__ __forceinline__ float wredsum(float v) {
#pragma unroll
  for (int off = 32; off > 0; off >>= 1) v += __shfl_xor(v, off, 64);
  return v;
}

__device__ __forceinline__ unsigned short f2bf(float x) {
  unsigned u = __float_as_uint(x);
  u = u + 0x7FFFu + ((u >> 16) & 1u);
  return (unsigned short)(u >> 16);
}

__device__ __forceinline__ unsigned packbf(float a, float b) {
  return (unsigned)f2bf(a) | ((unsigned)f2bf(b) << 16);
}

// ---------------- weight prep ----------------
// wt[2][256k][64co] fp32 (conv4/conv5 VALU path), k = ci*4+ky*2+kx
// wB bf16 MFMA B-fragments, value = W[k = ks*32 + (lane>>4)*8 + j][co = nt*16 + (lane&15)]
//   conv0 @0, conv1..3 @2048, ie_w1 @OFF_IE1, ie_w2 @OFF_IE2, em_w1 @OFF_EM1 (K pad 134->160),
//   em_w2 @OFF_EM2

__global__ __launch_bounds__(256) void prep_weights_kernel(
    const float* __restrict__ cw0, const float* __restrict__ cw, const float* __restrict__ ie_w1,
    const float* __restrict__ ie_w2, const float* __restrict__ em_w1,
    const float* __restrict__ em_w2, float* __restrict__ wt, unsigned short* __restrict__ wB) {
  int j = blockIdx.x * 256 + threadIdx.x;
  if (j < 2 * 16384) {  // fp32 weights for conv4 (l=3) and conv5 (l=4)
    int l = 3 + (j >> 14);
    int rem = j & 16383;
    int k = rem >> 6;
    int co = rem & 63;
    wt[j] = cw[(size_t)((l << 6) + co) * 256 + k];
    return;
  }
  int g = j - 2 * 16384;
  if (g < 2048) {
    int nt = g >> 9, lane = (g >> 3) & 63, jj = g & 7;
    int k = ((lane >> 4) << 3) + jj;
    int co = nt * 16 + (lane & 15);
    float v = (k < 12) ? cw0[co * 12 + k] : 0.f;
    wB[OFF_CONV0 + g] = f2bf(v);
    return;
  }
  g -= 2048;
  if (g < 3 * 16384) {
    int l = g >> 14;  // conv layers 1..3
    int r = g & 16383;
    int ks = r >> 11, nt = (r >> 9) & 3, lane = (r >> 3) & 63, jj = r & 7;
    int k = ks * 32 + ((lane >> 4) << 3) + jj;
    int co = nt * 16 + (lane & 15);
    wB[OFF_CONV13 + g] = f2bf(cw[(size_t)(((l << 6) + co) << 8) + k]);
    return;
  }
  g -= 3 * 16384;
  if (g < 4 * 12288) {  // ie_w1 [4][192][64]
    int l = g / 12288, r = g % 12288;
    int ks = r >> 11, nt = (r >> 9) & 3, lane = (r >> 3) & 63, jj = r & 7;
    int k = ks * 32 + ((lane >> 4) << 3) + jj;
    int co = nt * 16 + (lane & 15);
    wB[OFF_IE1 + g] = f2bf(ie_w1[(size_t)l * 12288 + k * 64 + co]);
    return;
  }
  g -= 4 * 12288;
  if (g < 4 * 4096) {  // ie_w2 [4][64][64]
    int l = g >> 12, r = g & 4095;
    int ks = r >> 11, nt = (r >> 9) & 3, lane = (r >> 3) & 63, jj = r & 7;
    int k = ks * 32 + ((lane >> 4) << 3) + jj;
    int co = nt * 16 + (lane & 15);
    wB[OFF_IE2 + g] = f2bf(ie_w2[(size_t)l * 4096 + k * 64 + co]);
    return;
  }
  g -= 4 * 4096;
  if (g < 20480) {  // em_w1 [134][128], K padded to 160
    int ks = g >> 12, r = g & 4095;
    int nt = r >> 9, lane = (r >> 3) & 63, jj = r & 7;
    int k = ks * 32 + ((lane >> 4) << 3) + jj;
    int co = nt * 16 + (lane & 15);
    float v = (k < 134) ? em_w1[(size_t)k * 128 + co] : 0.f;
    wB[OFF_EM1 + g] = f2bf(v);
    return;
  }
  g -= 20480;
  if (g < 8192) {  // em_w2 [128][64]
    int ks = g >> 11, r = g & 2047;
    int nt = (r >> 9) & 3, lane = (r >> 3) & 63, jj = r & 7;
    int k = ks * 32 + ((lane >> 4) << 3) + jj;
    int co = nt * 16 + (lane & 15);
    wB[OFF_EM2 + g] = f2bf(em_w2[(size_t)k * 64 + co]);
  }
}

// ---------------- fused conv stack (MFMA): crop[N,3,64,64] -> crop_feat[N,64] ----------------

__global__ __launch_bounds__(256) void conv_stack_kernel(
    const float* __restrict__ crop, const float* __restrict__ cb0,
    const unsigned short* __restrict__ wB, const float* __restrict__ wt,
    const float* __restrict__ cb, float* __restrict__ crop_feat) {
  __shared__ __align__(16) char pool[47360];
  unsigned short* sA0 = (unsigned short*)pool;
  unsigned short* sA1 = (unsigned short*)(pool + 5120);
  unsigned short* sA2 = (unsigned short*)(pool + 13568);
  unsigned short* sA3 = (unsigned short*)pool;
  float* s_o3 = (float*)(pool + 13568);
  float* s_o4 = (float*)(pool + 17664);
  float* s_red = (float*)(pool + 18688);

  const int t = threadIdx.x;
  const int lane = t & 63, wv = t >> 6;
  const int col = lane & 15, quad = lane >> 4;
  const int n = blockIdx.x;
  const float* cr = crop + (size_t)n * 12288;
  const int co = wv * 16 + col;

  for (int i = t; i < 64 * 28; i += 256) {
    int px = i / 28, kk = 12 + i - px * 28;
    sA0[px * A0_STRIDE + kk] = 0;
  }

  bf16x8 b0 = *(const bf16x8*)(wB + (wv * 64 + lane) * 8);
  bf16x8 b1f[8];
#pragma unroll
  for (int ks = 0; ks < 8; ks++)
    b1f[ks] = *(const bf16x8*)(wB + 2048 + ((ks * 4 + wv) * 64 + lane) * 8);

  const float bias0 = cb0[co];
  const float bias1 = cb[co];

  const int r0 = t >> 6, c0 = t & 63;
  const int a0base = ((r0 >> 1) * 32 + (c0 >> 1)) * A0_STRIDE + (r0 & 1) * 2 + (c0 & 1);
  float pf0 = cr[r0 * 64 + c0];
  float pf1 = cr[4096 + r0 * 64 + c0];
  float pf2 = cr[8192 + r0 * 64 + c0];

  for (int y1 = 0; y1 < 16; y1++) {
    sA0[a0base + 0] = f2bf(pf0);
    sA0[a0base + 4] = f2bf(pf1);
    sA0[a0base + 8] = f2bf(pf2);
    __syncthreads();
    if (y1 < 15) {
      const float* base = cr + (4 * (y1 + 1) + r0) * 64 + c0;
      pf0 = base[0];
      pf1 = base[4096];
      pf2 = base[8192];
    }
#pragma unroll
    for (int mt = 0; mt < 4; mt++) {
      f32x4 acc = {0.f, 0.f, 0.f, 0.f};
      bf16x8 a = *(const bf16x8*)(sA0 + (mt * 16 + col) * A0_STRIDE + quad * 8);
      acc = __builtin_amdgcn_mfma_f32_16x16x32_bf16(a, b0, acc, 0, 0, 0);
#pragma unroll
      for (int r = 0; r < 4; r += 2) {
        int px = mt * 16 + quad * 4 + r;
        int y = px >> 5, x = px & 31;
        float v0 = fmaxf(acc[r] + bias0, 0.f);
        float v1 = fmaxf(acc[r + 1] + bias0, 0.f);
        *(unsigned*)(sA1 + (x >> 1) * A_STRIDE + co * 4 + y * 2) = packbf(v0, v1);
      }
    }
    __syncthreads();
    f32x4 acc1 = {0.f, 0.f, 0.f, 0.f};
#pragma unroll
    for (int ks = 0; ks < 8; ks++) {
      bf16x8 a = *(const bf16x8*)(sA1 + col * A_STRIDE + ks * 32 + quad * 8);
      acc1 = __builtin_amdgcn_mfma_f32_16x16x32_bf16(a, b1f[ks], acc1, 0, 0, 0);
    }
#pragma unroll
    for (int r = 0; r < 4; r += 2) {
      int x1 = quad * 4 + r;
      float v0 = fmaxf(acc1[r] + bias1, 0.f);
      float v1 = fmaxf(acc1[r + 1] + bias1, 0.f);
      *(unsigned*)(sA2 + ((y1 >> 1) * 8 + (x1 >> 1)) * A_STRIDE + co * 4 + (y1 & 1) * 2) =
          packbf(v0, v1);
    }
    __syncthreads();
  }

  bf16x8 b2f[8], b3f[8];
#pragma unroll
  for (int ks = 0; ks < 8; ks++) {
    b2f[ks] = *(const bf16x8*)(wB + 18432 + ((ks * 4 + wv) * 64 + lane) * 8);
    b3f[ks] = *(const bf16x8*)(wB + 34816 + ((ks * 4 + wv) * 64 + lane) * 8);
  }
  const float bias2 = cb[64 + co];
  f32x4 a2acc[4];
#pragma unroll
  for (int mt = 0; mt < 4; mt++) {
    f32x4 acc = {0.f, 0.f, 0.f, 0.f};
#pragma unroll
    for (int ks = 0; ks < 8; ks++) {
      bf16x8 a = *(const bf16x8*)(sA2 + (mt * 16 + col) * A_STRIDE + ks * 32 + quad * 8);
      acc = __builtin_amdgcn_mfma_f32_16x16x32_bf16(a, b2f[ks], acc, 0, 0, 0);
    }
    a2acc[mt] = acc;
  }
  __syncthreads();
#pragma unroll
  for (int mt = 0; mt < 4; mt++) {
#pragma unroll
    for (int r = 0; r < 4; r += 2) {
      int px2 = mt * 16 + quad * 4 + r;
      int y2 = px2 >> 3, x2 = px2 & 7;
      float v0 = fmaxf(a2acc[mt][r] + bias2, 0.f);
      float v1 = fmaxf(a2acc[mt][r + 1] + bias2, 0.f);
      *(unsigned*)(sA3 + ((y2 >> 1) * 4 + (x2 >> 1)) * A_STRIDE + co * 4 + (y2 & 1) * 2) =
          packbf(v0, v1);
    }
  }
  __syncthreads();

  const float bias3 = cb[128 + co];
  {
    f32x4 acc = {0.f, 0.f, 0.f, 0.f};
#pragma unroll
    for (int ks = 0; ks < 8; ks++) {
      bf16x8 a = *(const bf16x8*)(sA3 + col * A_STRIDE + ks * 32 + quad * 8);
      acc = __builtin_amdgcn_mfma_f32_16x16x32_bf16(a, b3f[ks], acc, 0, 0, 0);
    }
    __syncthreads();
#pragma unroll
    for (int r = 0; r < 4; r++) {
      int px3 = quad * 4 + r;
      int y3 = px3 >> 2, x3 = px3 & 3;
      s_o3[(co * 4 + (y3 & 1) * 2 + (x3 & 1)) * 4 + (y3 >> 1) * 2 + (x3 >> 1)] =
          fmaxf(acc[r] + bias3, 0.f);
    }
  }
  __syncthreads();

  {
    const int p4 = t & 3, co4 = t >> 2;
    float a4 = 0.f;
    const float* w4p = wt + co4;
    for (int k = 0; k < 256; k++) a4 += s_o3[k * 4 + p4] * w4p[k * 64];
    s_o4[co4 * 4 + p4] = fmaxf(a4 + cb[192 + co4], 0.f);
  }
  __syncthreads();

  {
    const int co5 = t & 63, ks = t >> 6;
    float p = 0.f;
    const float* w5p = wt + 16384 + co5;
    for (int kk = 0; kk < 64; kk++) {
      int k = ks * 64 + kk;
      p += s_o4[k] * w5p[k * 64];
    }
    s_red[t] = p;
  }
  __syncthreads();
  if (t < 64) {
    float v = s_red[t] + s_red[64 + t] + s_red[128 + t] + s_red[192 + t];
    crop_feat[(size_t)n * 64 + t] = fmaxf(v + cb[256 + t], 0.f);
  }
}

// ---------------- node encoder ----------------

__global__ __launch_bounds__(256) void encode_nodes_kernel(
    const float* __restrict__ x, const float* __restrict__ cf, const float* __restrict__ nu_w,
    const float* __restrict__ nu_b, const float* __restrict__ nu_g, const float* __restrict__ nu_be,
    float* __restrict__ node) {
  const int lane = threadIdx.x & 63, wv = threadIdx.x >> 6;
  const int n = blockIdx.x * 4 + wv;
  const float* xr = x + (size_t)n * 32;
  const float* crf = cf + (size_t)n * 64;
  float acc = nu_b[lane];
  for (int k = 0; k < 32; k++) acc += xr[k] * nu_w[k * 64 + lane];
  for (int k = 0; k < 64; k++) acc += crf[k] * nu_w[(32 + k) * 64 + lane];
  float h = fmaxf(acc, 0.f);
  float mu = wredsum(h) * 0.015625f;
  float d = h - mu;
  float var = wredsum(d * d) * 0.015625f;
  node[(size_t)n * 64 + lane] = d * rsqrtf(var + LN_EPS) * nu_g[lane] + nu_be[lane];
}

// ---------------- edge encoder ----------------

__global__ __launch_bounds__(256) void encode_edges_kernel(
    const float* __restrict__ ea, const float* __restrict__ eu_w, const float* __restrict__ eu_b,
    const float* __restrict__ eu_g, const float* __restrict__ eu_be, float* __restrict__ ef) {
  const int lane = threadIdx.x & 63, wv = threadIdx.x >> 6;
  const int e = blockIdx.x * 4 + wv;
  const float* er = ea + (size_t)e * 6;
  float acc = eu_b[lane];
#pragma unroll
  for (int k = 0; k < 6; k++) acc += er[k] * eu_w[k * 64 + lane];
  float h = fmaxf(acc, 0.f);
  float mu = wredsum(h) * 0.015625f;
  float d = h - mu;
  float var = wredsum(d * d) * 0.015625f;
  ef[(size_t)e * 64 + lane] = d * rsqrtf(var + LN_EPS) * eu_g[lane] + eu_be[lane];
}

// ---------------- message (MFMA) + scatter-add ----------------
// 64 edges/block. A[64][192] bf16 in LDS (pad->200): [node[dst] | node[src] | ef].
// GEMM1 K=192 (6 ks), GEMM2 K=64 (2 ks); each wave owns one 16-col ntile.

__global__ __launch_bounds__(256) void message_mfma_kernel(
    const float* __restrict__ node, const float* __restrict__ ef, const int* __restrict__ ei,
    const unsigned short* __restrict__ wf1, const float* __restrict__ b1,
    const unsigned short* __restrict__ wf2, const float* __restrict__ b2,
    float* __restrict__ agg) {
  __shared__ __align__(16) unsigned short sA[64 * 200];
  __shared__ __align__(16) unsigned short sH[64 * 72];
  __shared__ int sD[64];
  const int t = threadIdx.x, lane = t & 63, wv = t >> 6;
  const int col = lane & 15, quad = lane >> 4;
  const int e0 = blockIdx.x * 64;

  bf16x8 bf1[6], bf2[2];
#pragma unroll
  for (int ks = 0; ks < 6; ks++)
    bf1[ks] = *(const bf16x8*)(wf1 + ((ks * 4 + wv) * 64 + lane) * 8);
#pragma unroll
  for (int ks = 0; ks < 2; ks++)
    bf2[ks] = *(const bf16x8*)(wf2 + ((ks * 4 + wv) * 64 + lane) * 8);

  if (t < 64) sD[t] = ei[NE + e0 + t];

#pragma unroll
  for (int i = 0; i < 16; i++) {
    int e = e0 + wv * 16 + i;
    int s = ei[e];
    int d = ei[NE + e];
    int row = wv * 16 + i;
    float vD = node[(size_t)d * 64 + lane];
    float vS = node[(size_t)s * 64 + lane];
    float vE = ef[(size_t)e * 64 + lane];
    sA[row * 200 + lane] = f2bf(vD);
    sA[row * 200 + 64 + lane] = f2bf(vS);
    sA[row * 200 + 128 + lane] = f2bf(vE);
  }
  __syncthreads();

  const float bb1 = b1[wv * 16 + col];
  f32x4 acc[4];
#pragma unroll
  for (int mt = 0; mt < 4; mt++) {
    f32x4 a4 = {0.f, 0.f, 0.f, 0.f};
#pragma unroll
    for (int ks = 0; ks < 6; ks++) {
      bf16x8 a = *(const bf16x8*)(sA + (mt * 16 + col) * 200 + ks * 32 + quad * 8);
      a4 = __builtin_amdgcn_mfma_f32_16x16x32_bf16(a, bf1[ks], a4, 0, 0, 0);
    }
    acc[mt] = a4;
  }
#pragma unroll
  for (int mt = 0; mt < 4; mt++) {
#pragma unroll
    for (int r = 0; r < 4; r++) {
      int row = mt * 16 + quad * 4 + r;
      sH[row * 72 + wv * 16 + col] = f2bf(fmaxf(acc[mt][r] + bb1, 0.f));
    }
  }
  __syncthreads();

  const float bb2 = b2[wv * 16 + col];
#pragma unroll
  for (int mt = 0; mt < 4; mt++) {
    f32x4 a4 = {0.f, 0.f, 0.f, 0.f};
#pragma unroll
    for (int ks = 0; ks < 2; ks++) {
      bf16x8 a = *(const bf16x8*)(sH + (mt * 16 + col) * 72 + ks * 32 + quad * 8);
      a4 = __builtin_amdgcn_mfma_f32_16x16x32_bf16(a, bf2[ks], a4, 0, 0, 0);
    }
#pragma unroll
    for (int r = 0; r < 4; r++) {
      int row = mt * 16 + quad * 4 + r;
      atomicAdd(agg + (size_t)sD[row] * 64 + wv * 16 + col, a4[r] + bb2);
    }
  }
}

// ---------------- node update (fp32 VALU, small) ----------------

__global__ __launch_bounds__(256) void node_update_kernel(
    const float* __restrict__ node, const float* __restrict__ agg, const float* __restrict__ w1,
    const float* __restrict__ b1, const float* __restrict__ w2, const float* __restrict__ b2,
    float* __restrict__ out) {
  __shared__ float s_w[8192];
  for (int i = threadIdx.x; i < 8192; i += 256) s_w[i] = w1[i];
  __syncthreads();
  const int lane = threadIdx.x & 63, wv = threadIdx.x >> 6;
  const int n0 = blockIdx.x * 32 + wv * 8;
  const float* rN[8];
  const float* rA[8];
  float acc[8];
  const float bb = b1[lane];
#pragma unroll
  for (int i = 0; i < 8; i++) {
    int n = (n0 + i < NN) ? (n0 + i) : 0;
    rN[i] = node + (size_t)n * 64;
    rA[i] = agg + (size_t)n * 64;
    acc[i] = bb;
  }
  for (int k = 0; k < 64; k++) {
    float w = s_w[k * 64 + lane];
#pragma unroll
    for (int i = 0; i < 8; i++) acc[i] += rN[i][k] * w;
  }
  for (int k = 0; k < 64; k++) {
    float w = s_w[(64 + k) * 64 + lane];
#pragma unroll
    for (int i = 0; i < 8; i++) acc[i] += rA[i][k] * w;
  }
  float h[8];
#pragma unroll
  for (int i = 0; i < 8; i++) h[i] = fmaxf(acc[i], 0.f);
  float m[8];
  const float b2v = b2[lane];
#pragma unroll
  for (int i = 0; i < 8; i++) m[i] = b2v;
  for (int k = 0; k < 64; k++) {
    float w = w2[k * 64 + lane];
#pragma unroll
    for (int i = 0; i < 8; i++) m[i] += __shfl(h[i], k, 64) * w;
  }
#pragma unroll
  for (int i = 0; i < 8; i++)
    if (n0 + i < NN) out[(size_t)(n0 + i) * 64 + lane] = m[i];
}

// ---------------- final edge MLP (MFMA) ----------------
// 64 edges/block. A[64][160] bf16 (pad->168): [node[src] | node[dst] | ea | 0...].
// GEMM1 K=160 (5 ks) N=128 (wave owns ntiles wv, wv+4); GEMM2 K=128 (4 ks) N=64;
// then h2 @ w3 reduced per-edge with wave shuffles.

__global__ __launch_bounds__(256) void final_mfma_kernel(
    const float* __restrict__ node, const float* __restrict__ ea, const int* __restrict__ ei,
    const unsigned short* __restrict__ wf1, const float* __restrict__ b1,
    const unsigned short* __restrict__ wf2, const float* __restrict__ b2,
    const float* __restrict__ w3, const float* __restrict__ b3, float* __restrict__ out) {
  __shared__ __align__(16) char pool[21504 + 17408];
  unsigned short* sA = (unsigned short*)pool;             // [64][168] bf16
  unsigned short* sH1 = (unsigned short*)(pool + 21504);  // [64][136] bf16
  float* sH2 = (float*)pool;                              // [64][68] fp32, aliases sA (dead)
  const int t = threadIdx.x, lane = t & 63, wv = t >> 6;
  const int col = lane & 15, quad = lane >> 4;
  const int e0 = blockIdx.x * 64;

  bf16x8 bw1[5][2], bw2[4];
#pragma unroll
  for (int ks = 0; ks < 5; ks++) {
    bw1[ks][0] = *(const bf16x8*)(wf1 + ((ks * 8 + wv) * 64 + lane) * 8);
    bw1[ks][1] = *(const bf16x8*)(wf1 + ((ks * 8 + wv + 4) * 64 + lane) * 8);
  }
#pragma unroll
  for (int ks = 0; ks < 4; ks++)
    bw2[ks] = *(const bf16x8*)(wf2 + ((ks * 4 + wv) * 64 + lane) * 8);

#pragma unroll
  for (int i = 0; i < 16; i++) {
    int e = e0 + wv * 16 + i;
    int s = ei[e];
    int d = ei[NE + e];
    int row = wv * 16 + i;
    float vS = node[(size_t)s * 64 + lane];
    float vD = node[(size_t)d * 64 + lane];
    sA[row * 168 + lane] = f2bf(vS);
    sA[row * 168 + 64 + lane] = f2bf(vD);
    if (lane < 32) {
      float v = (lane < 6) ? ea[(size_t)e * 6 + lane] : 0.f;
      sA[row * 168 + 128 + lane] = f2bf(v);
    }
  }
  __syncthreads();

  const float bb1a = b1[wv * 16 + col];
  const float bb1b = b1[64 + wv * 16 + col];
  f32x4 acc[4][2];
#pragma unroll
  for (int mt = 0; mt < 4; mt++) {
    f32x4 a0 = {0.f, 0.f, 0.f, 0.f};
    f32x4 a1 = {0.f, 0.f, 0.f, 0.f};
#pragma unroll
    for (int ks = 0; ks < 5; ks++) {
      bf16x8 a = *(const bf16x8*)(sA + (mt * 16 + col) * 168 + ks * 32 + quad * 8);
      a0 = __builtin_amdgcn_mfma_f32_16x16x32_bf16(a, bw1[ks][0], a0, 0, 0, 0);
      a1 = __builtin_amdgcn_mfma_f32_16x16x32_bf16(a, bw1[ks][1], a1, 0, 0, 0);
    }
    acc[mt][0] = a0;
    acc[mt][1] = a1;
  }
#pragma unroll
  for (int mt = 0; mt < 4; mt++) {
#pragma unroll
    for (int r = 0; r < 4; r++) {
      int row = mt * 16 + quad * 4 + r;
      sH1[row * 136 + wv * 16 + col] = f2bf(fmaxf(acc[mt][0][r] + bb1a, 0.f));
      sH1[row * 136 + 64 + wv * 16 + col] = f2bf(fmaxf(acc[mt][1][r] + bb1b, 0.f));
    }
  }
  __syncthreads();

  const float bb2 = b2[wv * 16 + col];
#pragma unroll
  for (int mt = 0; mt < 4; mt++) {
    f32x4 a4 = {0.f, 0.f, 0.f, 0.f};
#pragma unroll
    for (int ks = 0; ks < 4; ks++) {
      bf16x8 a = *(const bf16x8*)(sH1 + (mt * 16 + col) * 136 + ks * 32 + quad * 8);
      a4 = __builtin_amdgcn_mfma_f32_16x16x32_bf16(a, bw2[ks], a4, 0, 0, 0);
    }
#pragma unroll
    for (int r = 0; r < 4; r++) {
      int row = mt * 16 + quad * 4 + r;
      sH2[row * 68 + wv * 16 + col] = fmaxf(a4[r] + bb2, 0.f);
    }
  }
  __syncthreads();

  const float w3v = w3[lane];
  const float b3v = b3[0];
#pragma unroll
  for (int i = 0; i < 16; i++) {
    int row = wv * 16 + i;
    float v = wredsum(sH2[row * 68 + lane] * w3v);
    if (lane == 0) out[e0 + row] = v + b3v;
  }
}

// ---------------- launch ----------------

extern "C" void kernel_launch(void* const* d_in, const int* in_sizes, int n_in, void* d_out,
                              int out_size, void* d_ws, size_t ws_size, hipStream_t stream) {
  const float* x = (const float*)d_in[0];
  const int* ei = (const int*)d_in[1];
  const float* ea = (const float*)d_in[2];
  const float* crop = (const float*)d_in[3];
  const float* cw0 = (const float*)d_in[4];
  const float* cb0 = (const float*)d_in[5];
  const float* cw = (const float*)d_in[6];
  const float* cb = (const float*)d_in[7];
  const float* nu_w = (const float*)d_in[8];
  const float* nu_b = (const float*)d_in[9];
  const float* nu_g = (const float*)d_in[10];
  const float* nu_be = (const float*)d_in[11];
  const float* eu_w = (const float*)d_in[12];
  const float* eu_b = (const float*)d_in[13];
  const float* eu_g = (const float*)d_in[14];
  const float* eu_be = (const float*)d_in[15];
  const float* ie_w1 = (const float*)d_in[16];
  const float* ie_b1 = (const float*)d_in[17];
  const float* ie_w2 = (const float*)d_in[18];
  const float* ie_b2 = (const float*)d_in[19];
  const float* in_w1 = (const float*)d_in[20];
  const float* in_b1 = (const float*)d_in[21];
  const float* in_w2 = (const float*)d_in[22];
  const float* in_b2 = (const float*)d_in[23];
  const float* em_w1 = (const float*)d_in[24];
  const float* em_b1 = (const float*)d_in[25];
  const float* em_w2 = (const float*)d_in[26];
  const float* em_b2 = (const float*)d_in[27];
  const float* em_w3 = (const float*)d_in[28];
  const float* em_b3 = (const float*)d_in[29];
  float* out = (float*)d_out;

  float* ws = (float*)d_ws;
  float* wt = ws;                                       // 32768 f (conv4/conv5 fp32)
  unsigned short* wB = (unsigned short*)(ws + 32768);   // 145408 bf16 = 72704 f
  float* crop_feat = ws + 32768 + 72704;
  float* node_a = crop_feat + 640000;
  float* node_b = node_a + 640000;
  float* agg = node_b + 640000;
  float* edge_f = agg + 640000;  // NE*64

  // total prep elements: 32768 + 145408 = 178176 -> 696 blocks of 256
  prep_weights_kernel<<<dim3(696), dim3(256), 0, stream>>>(cw0, cw, ie_w1, ie_w2, em_w1, em_w2, wt,
                                                           wB);
  conv_stack_kernel<<<dim3(NN), dim3(256), 0, stream>>>(crop, cb0, wB, wt, cb, crop_feat);
  encode_nodes_kernel<<<dim3(NN / 4), dim3(256), 0, stream>>>(x, crop_feat, nu_w, nu_b, nu_g,
                                                              nu_be, node_a);
  encode_edges_kernel<<<dim3(NE / 4), dim3(256), 0, stream>>>(ea, eu_w, eu_b, eu_g, eu_be, edge_f);

  const float* ncur = node_a;
  float* nnext = node_b;
  for (int l = 0; l < 4; l++) {
    hipMemsetAsync(agg, 0, (size_t)640000 * sizeof(float), stream);
    message_mfma_kernel<<<dim3(NE / 64), dim3(256), 0, stream>>>(
        ncur, edge_f, ei, wB + OFF_IE1 + l * 12288, ie_b1 + l * 64, wB + OFF_IE2 + l * 4096,
        ie_b2 + l * 64, agg);
    node_update_kernel<<<dim3((NN + 31) / 32), dim3(256), 0, stream>>>(
        ncur, agg, in_w1 + (size_t)l * 8192, in_b1 + l * 64, in_w2 + (size_t)l * 4096,
        in_b2 + l * 64, nnext);
    float* tmp = (float*)ncur;
    ncur = nnext;
    nnext = tmp;
  }
  final_mfma_kernel<<<dim3(NE / 64), dim3(256), 0, stream>>>(ncur, ea, ei, wB + OFF_EM1, em_b1,
                                                             wB + OFF_EM2, em_b2, em_w3, em_b3,
                                                             out);
}